// Round 1
// baseline (2769.355 us; speedup 1.0000x reference)
//
#include <hip/hip_runtime.h>
#include <hip/hip_bf16.h>
#include <math.h>

typedef __bf16 bf16;
typedef __bf16 bf16x8 __attribute__((ext_vector_type(8)));
typedef __bf16 bf16x4 __attribute__((ext_vector_type(4)));
typedef float  f32x4  __attribute__((ext_vector_type(4)));

#define MFMA(a,b,c) __builtin_amdgcn_mfma_f32_16x16x32_bf16((a),(b),(c),0,0,0)

constexpr int LDT = 40;   // padded LDS leading dim (bf16 elems): 80B stride -> 2-way bank alias only (free)

__device__ __forceinline__ float wave_sum(float v){
#pragma unroll
  for(int off=1; off<64; off<<=1) v += __shfl_xor(v, off);
  return v;
}

// ---------------- fused (add) + layernorm -> bf16 ----------------
// one block per row of 1024; 256 threads * 4 floats
__global__ __launch_bounds__(256) void add_ln_kernel(
    const float* __restrict__ xsrc, const float* __restrict__ addsrc,
    const float* __restrict__ emb,
    const float* __restrict__ gw, const float* __restrict__ gb,
    float* __restrict__ xout, bf16* __restrict__ hout)
{
  const int row = blockIdx.x;
  const int t = threadIdx.x;
  const size_t rbase = (size_t)row * 1024;
  float4 x = ((const float4*)(xsrc + rbase))[t];
  if(addsrc){
    float4 a = ((const float4*)(addsrc + rbase))[t];
    x.x += a.x; x.y += a.y; x.z += a.z; x.w += a.w;
  }
  if(emb){
    float4 e = ((const float4*)emb)[t];
    x.x += e.x; x.y += e.y; x.z += e.z; x.w += e.w;
  }
  if(xout) ((float4*)(xout + rbase))[t] = x;

  float s = x.x + x.y + x.z + x.w;
  float q = x.x*x.x + x.y*x.y + x.z*x.z + x.w*x.w;
  s = wave_sum(s); q = wave_sum(q);
  __shared__ float red[8];
  const int w = t >> 6;
  if((t & 63) == 0){ red[w] = s; red[4+w] = q; }
  __syncthreads();
  s = red[0]+red[1]+red[2]+red[3];
  q = red[4]+red[5]+red[6]+red[7];
  const float mean = s * (1.0f/1024.0f);
  const float var  = q * (1.0f/1024.0f) - mean*mean;
  const float inv  = rsqrtf(var + 1e-5f);

  float4 wv = ((const float4*)gw)[t];
  float4 bv = ((const float4*)gb)[t];
  bf16x4 hv;
  hv[0] = (bf16)((x.x - mean)*inv*wv.x + bv.x);
  hv[1] = (bf16)((x.y - mean)*inv*wv.y + bv.y);
  hv[2] = (bf16)((x.z - mean)*inv*wv.z + bv.z);
  hv[3] = (bf16)((x.w - mean)*inv*wv.w + bv.w);
  *(bf16x4*)(hout + rbase + t*4) = hv;
}

// ---------------- weight packing ----------------
// Wq [H=16, D=1024, HD=64] fp32 -> WqT [N=1024][K=1024] bf16 with N = h*64+kk, WqT[n][d]=Wq[h][d][kk]
__global__ __launch_bounds__(256) void pack_qkv_kernel(const float* __restrict__ W, bf16* __restrict__ Wt){
  const int i = blockIdx.x*256 + threadIdx.x;      // over 1M outputs
  const int n = i >> 10, d = i & 1023;
  const int h = n >> 6, kk = n & 63;
  Wt[i] = (bf16)W[h*65536 + d*64 + kk];
}
// W [K][N] fp32 -> Wt [N][K] bf16
__global__ __launch_bounds__(256) void pack_t_kernel(const float* __restrict__ W, bf16* __restrict__ Wt, int Kd, int Nd){
  const int i = blockIdx.x*256 + threadIdx.x;
  const int n = i / Kd, k = i - n*Kd;
  Wt[i] = (bf16)W[(size_t)k*Nd + n];
}

// ---------------- bf16 MFMA GEMM:  C[M=4096,N] = A[M,K] * Bt[N,K]^T ----------------
// tile 64(M) x 128(N), BK=32, 256 threads = 4 waves side by side in N (32 cols each)
// EPI: 0 plain->bf16 ; 1 +bias->bf16 ; 2 x1 = res + acc + bias -> f32 ; 3 out = res + gelu(acc+bias) -> f32
template<int EPI>
__global__ __launch_bounds__(256) void gemm_kernel(
    const bf16* __restrict__ A, const bf16* __restrict__ Bt,
    float* __restrict__ outf, bf16* __restrict__ outb,
    const float* __restrict__ bias, const float* __restrict__ res,
    int N, int K)
{
  __shared__ __align__(16) bf16 As[64*LDT];
  __shared__ __align__(16) bf16 Bs[128*LDT];
  const int tid  = threadIdx.x;
  const int lane = tid & 63;
  const int w    = tid >> 6;
  const int quad = lane >> 4;
  const int l16  = lane & 15;
  const int tm = blockIdx.y, tn = blockIdx.x;

  // staging: thread -> (row = tid/4, 8-elem chunk = tid%4)
  const int srow = tid >> 2;
  const int soff = (tid & 3) * 8;
  const bf16* Ag  = A  + (size_t)(tm*64  + srow)*K + soff;
  const bf16* Bg0 = Bt + (size_t)(tn*128 + srow)*K + soff;
  const bf16* Bg1 = Bg0 + (size_t)64*K;
  bf16* Asw  = As + srow*LDT + soff;
  bf16* Bsw0 = Bs + srow*LDT + soff;
  bf16* Bsw1 = Bsw0 + 64*LDT;
  const bf16* Ar = As + l16*LDT + quad*8;                 // A frag: m=lane&15, k=quad*8+j
  const bf16* Br = Bs + (w*32 + l16)*LDT + quad*8;        // B frag from Bt rows: n=lane&15, k=quad*8+j

  f32x4 acc[4][2] = {};

  for(int k0 = 0; k0 < K; k0 += 32){
    *(bf16x8*)Asw  = *(const bf16x8*)Ag;
    *(bf16x8*)Bsw0 = *(const bf16x8*)Bg0;
    *(bf16x8*)Bsw1 = *(const bf16x8*)Bg1;
    Ag += 32; Bg0 += 32; Bg1 += 32;
    __syncthreads();
    bf16x8 af[4], bfr[2];
#pragma unroll
    for(int r=0;r<4;r++) af[r]  = *(const bf16x8*)(Ar + r*16*LDT);
#pragma unroll
    for(int c=0;c<2;c++) bfr[c] = *(const bf16x8*)(Br + c*16*LDT);
#pragma unroll
    for(int r=0;r<4;r++)
#pragma unroll
      for(int c=0;c<2;c++)
        acc[r][c] = MFMA(af[r], bfr[c], acc[r][c]);
    __syncthreads();
  }

  // C/D layout: col = lane&15, row = quad*4 + reg   [m89/m91 verified]
#pragma unroll
  for(int r=0;r<4;r++){
    const int grow0 = tm*64 + r*16 + quad*4;
#pragma unroll
    for(int c=0;c<2;c++){
      const int gcol = tn*128 + w*32 + c*16 + l16;
      const float bv = (EPI==0) ? 0.0f : bias[gcol];
#pragma unroll
      for(int g=0; g<4; g++){
        const size_t idx = (size_t)(grow0 + g)*N + gcol;
        const float v = acc[r][c][g] + bv;
        if(EPI <= 1){
          outb[idx] = (bf16)v;
        } else if(EPI == 2){
          outf[idx] = res[idx] + v;
        } else {
          const float gel = 0.5f*v*(1.0f + erff(v*0.70710678118654752f));
          outf[idx] = res[idx] + gel;
        }
      }
    }
  }
}

// ---------------- fused causal attention (flash-style, MFMA) ----------------
// Q/K/V/O: bf16 [4096][1024], element (b,t,h,kk) at (b*1024+t)*1024 + h*64 + kk
// grid: x = qtile (T/64 = 16), y = b*16+h (64). 256 thr = 4 waves, wave owns 16 q-rows.
__global__ __launch_bounds__(256) void attn_kernel(
    const bf16* __restrict__ Q, const bf16* __restrict__ Km,
    const bf16* __restrict__ V, bf16* __restrict__ O)
{
  const int qtile = blockIdx.x;
  const int bh = blockIdx.y;
  const int b = bh >> 4, h = bh & 15;
  const int tid = threadIdx.x;
  const int w = tid >> 6, lane = tid & 63;
  const int quad = lane >> 4, l16 = lane & 15;
  const size_t base = (size_t)b*1024*1024 + (size_t)h*64;
  const int qrow0 = qtile*64 + w*16;

  __shared__ __align__(16) bf16 pbuf[4][16*LDT];   // per-wave P tile (C-layout -> A-layout transform)
  bf16* pl = pbuf[w];

  const bf16* qp = Q + base + (size_t)(qrow0 + l16)*1024 + quad*8;
  bf16x8 aq0 = *(const bf16x8*)qp;          // A frag, hd 0..31
  bf16x8 aq1 = *(const bf16x8*)(qp + 32);   // A frag, hd 32..63

  f32x4 o[4] = {};
  float mrun[4] = {-INFINITY,-INFINITY,-INFINITY,-INFINITY};
  float lrun[4] = {0.f,0.f,0.f,0.f};
  const f32x4 zf = {0.f,0.f,0.f,0.f};

  const int kend = qrow0 + 16;              // keys 0..qrow0+15 needed
  for(int kb = 0; kb < kend; kb += 32){
    const bf16* kp = Km + base + (size_t)(kb + l16)*1024 + quad*8;
    bf16x8 b00 = *(const bf16x8*)kp;                              // keys kb..kb+15,  hd 0..31
    bf16x8 b01 = *(const bf16x8*)(kp + 32);                       //                  hd 32..63
    bf16x8 b10 = *(const bf16x8*)(kp + (size_t)16*1024);          // keys kb+16..kb+31
    bf16x8 b11 = *(const bf16x8*)(kp + (size_t)16*1024 + 32);
    f32x4 s0 = MFMA(aq0, b00, zf); s0 = MFMA(aq1, b01, s0);
    f32x4 s1 = MFMA(aq0, b10, zf); s1 = MFMA(aq1, b11, s1);

    const int col0 = kb + l16, col1 = col0 + 16;
#pragma unroll
    for(int r=0;r<4;r++){
      const int row = qrow0 + quad*4 + r;
      float v0 = (col0 <= row) ? s0[r]*0.03125f : -INFINITY;   // scale = 1024^-0.5
      float v1 = (col1 <= row) ? s1[r]*0.03125f : -INFINITY;
      float mx = fmaxf(v0, v1);
#pragma unroll
      for(int off=1; off<16; off<<=1) mx = fmaxf(mx, __shfl_xor(mx, off));
      const float mnew = fmaxf(mrun[r], mx);                   // finite from first block on
      const float alpha = __expf(mrun[r] - mnew);
      const float p0 = __expf(v0 - mnew);
      const float p1 = __expf(v1 - mnew);
      float rs = p0 + p1;
#pragma unroll
      for(int off=1; off<16; off<<=1) rs += __shfl_xor(rs, off);
      lrun[r] = lrun[r]*alpha + rs;
      mrun[r] = mnew;
#pragma unroll
      for(int c=0;c<4;c++) o[c][r] *= alpha;
      pl[(quad*4+r)*LDT + l16]      = (bf16)p0;
      pl[(quad*4+r)*LDT + 16 + l16] = (bf16)p1;
    }
    // P: C-layout -> A-layout via per-wave LDS (no __syncthreads: per-wave only, in-order DS ops)
    bf16x8 ap = *(const bf16x8*)(pl + l16*LDT + quad*8);
    const bf16* vp = V + base + (size_t)(kb + quad*8)*1024 + l16;
#pragma unroll
    for(int c=0;c<4;c++){
      bf16x8 bv;
#pragma unroll
      for(int j=0;j<8;j++) bv[j] = vp[(size_t)j*1024 + c*16];  // B frag: k=quad*8+j, n=lane&15
      o[c] = MFMA(ap, bv, o[c]);
    }
  }

#pragma unroll
  for(int c=0;c<4;c++){
#pragma unroll
    for(int r=0;r<4;r++){
      const int row = qrow0 + quad*4 + r;
      O[base + (size_t)row*1024 + c*16 + l16] = (bf16)(o[c][r] / lrun[r]);
    }
  }
}

// ---------------- launch ----------------
extern "C" void kernel_launch(void* const* d_in, const int* in_sizes, int n_in,
                              void* d_out, int out_size, void* d_ws, size_t ws_size,
                              hipStream_t stream)
{
  const float* x_in = (const float*)d_in[0];
  const float* emb  = (const float*)d_in[1];
  const float* Wq   = (const float*)d_in[2];
  const float* Wk   = (const float*)d_in[3];
  const float* Wv   = (const float*)d_in[4];
  const float* fcw  = (const float*)d_in[5];
  const float* fcb  = (const float*)d_in[6];
  const float* ln1w = (const float*)d_in[7];
  const float* ln1b = (const float*)d_in[8];
  const float* ln2w = (const float*)d_in[9];
  const float* ln2b = (const float*)d_in[10];
  const float* w1   = (const float*)d_in[11];
  const float* b1   = (const float*)d_in[12];
  const float* w2   = (const float*)d_in[13];
  const float* b2   = (const float*)d_in[14];
  const float* w3   = (const float*)d_in[15];
  const float* b3   = (const float*)d_in[16];

  char* ws = (char*)d_ws;
  const size_t MB = 1024*1024;
  float* cur   = (float*)(ws + 0);        // fp32 residual stream [4096,1024]
  float* x1    = (float*)(ws + 16*MB);    // fp32 x after attention residual
  float* newe  = (float*)(ws + 32*MB);    // fp32 block output
  bf16*  hb    = (bf16*)(ws + 48*MB);     // h (LN1 out) / h2 (LN2 out)
  bf16*  attnb = (bf16*)(ws + 56*MB);     // attn concat / m2
  bf16*  qb    = (bf16*)(ws + 64*MB);
  bf16*  kb    = (bf16*)(ws + 72*MB);
  bf16*  vb    = (bf16*)(ws + 80*MB);
  bf16*  m1b   = (bf16*)(ws + 88*MB);     // [4096,2048]
  bf16*  wqT   = (bf16*)(ws + 104*MB);
  bf16*  wkT   = (bf16*)(ws + 106*MB);
  bf16*  wvT   = (bf16*)(ws + 108*MB);
  bf16*  fcT   = (bf16*)(ws + 110*MB);
  bf16*  w1T   = (bf16*)(ws + 112*MB);    // [2048][1024]
  bf16*  w2T   = (bf16*)(ws + 116*MB);    // [1024][2048]
  bf16*  w3T   = (bf16*)(ws + 120*MB);    // [1024][1024]  end = 122 MB

  // weight packing (bf16, [N][K] transposed) — once per call
  pack_qkv_kernel<<<4096,256,0,stream>>>(Wq, wqT);
  pack_qkv_kernel<<<4096,256,0,stream>>>(Wk, wkT);
  pack_qkv_kernel<<<4096,256,0,stream>>>(Wv, wvT);
  pack_t_kernel<<<4096,256,0,stream>>>(fcw, fcT, 1024, 1024);
  pack_t_kernel<<<8192,256,0,stream>>>(w1,  w1T, 1024, 2048);
  pack_t_kernel<<<8192,256,0,stream>>>(w2,  w2T, 2048, 1024);
  pack_t_kernel<<<4096,256,0,stream>>>(w3,  w3T, 1024, 1024);

  const dim3 g1024(8, 64), g2048(16, 64);
  for(int t=0; t<8; t++){
    const float* xs = (t==0) ? x_in : cur;
    const float* as = (t==0) ? x_in : newe;
    // cur = xs + as + emb[t];  h = LN1(cur)
    add_ln_kernel<<<4096,256,0,stream>>>(xs, as, emb + t*1024, ln1w, ln1b, cur, hb);
    // q,k,v = h @ W{q,k,v}  (per-head concat layout)
    gemm_kernel<0><<<g1024,256,0,stream>>>(hb, wqT, nullptr, qb, nullptr, nullptr, 1024, 1024);
    gemm_kernel<0><<<g1024,256,0,stream>>>(hb, wkT, nullptr, kb, nullptr, nullptr, 1024, 1024);
    gemm_kernel<0><<<g1024,256,0,stream>>>(hb, wvT, nullptr, vb, nullptr, nullptr, 1024, 1024);
    // causal softmax attention
    attn_kernel<<<dim3(16,64),256,0,stream>>>(qb, kb, vb, attnb);
    // x1 = cur + attn @ fc_w + fc_b
    gemm_kernel<2><<<g1024,256,0,stream>>>(attnb, fcT, x1, nullptr, fcb, cur, 1024, 1024);
    // h2 = LN2(x1)
    add_ln_kernel<<<4096,256,0,stream>>>(x1, nullptr, nullptr, ln2w, ln2b, nullptr, hb);
    // m1 = h2 @ w1 + b1 ; m2 = m1 @ w2 + b2 ; out = x1 + gelu(m2 @ w3 + b3)
    gemm_kernel<1><<<g2048,256,0,stream>>>(hb,    w1T, nullptr, m1b,   b1, nullptr, 2048, 1024);
    gemm_kernel<1><<<g1024,256,0,stream>>>(m1b,   w2T, nullptr, attnb, b2, nullptr, 1024, 2048);
    float* mout = (t==7) ? (float*)d_out : newe;
    gemm_kernel<3><<<g1024,256,0,stream>>>(attnb, w3T, mout, nullptr, b3, x1, 1024, 1024);
  }
}

// Round 2
// 2148.372 us; speedup vs baseline: 1.2890x; 1.2890x over previous
//
#include <hip/hip_runtime.h>
#include <hip/hip_bf16.h>
#include <math.h>

typedef __bf16 bf16;
typedef __bf16 bf16x8 __attribute__((ext_vector_type(8)));
typedef __bf16 bf16x4 __attribute__((ext_vector_type(4)));
typedef float  f32x4  __attribute__((ext_vector_type(4)));

#define MFMA(a,b,c) __builtin_amdgcn_mfma_f32_16x16x32_bf16((a),(b),(c),0,0,0)
// async global->LDS, 16B per lane; LDS dest is wave-uniform base + lane*16 (m104/m108)
#define GLL16(gp, lp) __builtin_amdgcn_global_load_lds(\
    (const __attribute__((address_space(1))) void*)(gp), \
    (__attribute__((address_space(3))) void*)(lp), 16, 0, 0)

__device__ __forceinline__ float wave_sum(float v){
#pragma unroll
  for(int off=1; off<64; off<<=1) v += __shfl_xor(v, off);
  return v;
}

// ---------------- fused (add) + layernorm -> bf16 ----------------
__global__ __launch_bounds__(256) void add_ln_kernel(
    const float* __restrict__ xsrc, const float* __restrict__ addsrc,
    const float* __restrict__ emb,
    const float* __restrict__ gw, const float* __restrict__ gb,
    float* __restrict__ xout, bf16* __restrict__ hout)
{
  const int row = blockIdx.x;
  const int t = threadIdx.x;
  const size_t rbase = (size_t)row * 1024;
  float4 x = ((const float4*)(xsrc + rbase))[t];
  if(addsrc){
    float4 a = ((const float4*)(addsrc + rbase))[t];
    x.x += a.x; x.y += a.y; x.z += a.z; x.w += a.w;
  }
  if(emb){
    float4 e = ((const float4*)emb)[t];
    x.x += e.x; x.y += e.y; x.z += e.z; x.w += e.w;
  }
  if(xout) ((float4*)(xout + rbase))[t] = x;

  float s = x.x + x.y + x.z + x.w;
  float q = x.x*x.x + x.y*x.y + x.z*x.z + x.w*x.w;
  s = wave_sum(s); q = wave_sum(q);
  __shared__ float red[8];
  const int w = t >> 6;
  if((t & 63) == 0){ red[w] = s; red[4+w] = q; }
  __syncthreads();
  s = red[0]+red[1]+red[2]+red[3];
  q = red[4]+red[5]+red[6]+red[7];
  const float mean = s * (1.0f/1024.0f);
  const float var  = q * (1.0f/1024.0f) - mean*mean;
  const float inv  = rsqrtf(var + 1e-5f);

  float4 wv = ((const float4*)gw)[t];
  float4 bv = ((const float4*)gb)[t];
  bf16x4 hv;
  hv[0] = (bf16)((x.x - mean)*inv*wv.x + bv.x);
  hv[1] = (bf16)((x.y - mean)*inv*wv.y + bv.y);
  hv[2] = (bf16)((x.z - mean)*inv*wv.z + bv.z);
  hv[3] = (bf16)((x.w - mean)*inv*wv.w + bv.w);
  *(bf16x4*)(hout + rbase + t*4) = hv;
}

// ---------------- weight packing ----------------
__global__ __launch_bounds__(256) void pack_qkv_kernel(const float* __restrict__ W, bf16* __restrict__ Wt){
  const int i = blockIdx.x*256 + threadIdx.x;
  const int n = i >> 10, d = i & 1023;
  const int h = n >> 6, kk = n & 63;
  Wt[i] = (bf16)W[h*65536 + d*64 + kk];
}
__global__ __launch_bounds__(256) void pack_t_kernel(const float* __restrict__ W, bf16* __restrict__ Wt, int Kd, int Nd){
  const int i = blockIdx.x*256 + threadIdx.x;
  const int n = i / Kd, k = i - n*Kd;
  Wt[i] = (bf16)W[(size_t)k*Nd + n];
}

// ---------------- bf16 MFMA GEMM (m97 structure):  C[M,N] = A[M,K] * Bt[N,K]^T ----------------
// block: BLKM x 128, BK=32, 256 thr = 4 waves (2x2), wave tile (BLKM/2) x 64
// LDS K-major rows of 32 elems (64B), NO padding (global_load_lds constraint)
// EPI: 1 +bias->bf16 ; 2 res+acc+bias->f32 ; 3 res+gelu(acc+bias)->f32 ; 4 qkv 3-way split ->bf16
template<int EPI, int BLKM>
__global__ __launch_bounds__(256,2) void gemm_kernel(
    const bf16* __restrict__ A, const bf16* __restrict__ Bt,
    float* __restrict__ outf, bf16* __restrict__ outb,
    bf16* __restrict__ o2, bf16* __restrict__ o3,
    const float* __restrict__ bias, const float* __restrict__ res,
    int N, int K)
{
  constexpr int RM = BLKM/32;      // wave m-subtiles
  constexpr int HM = BLKM/2;       // wave m extent
  __shared__ __align__(16) bf16 As[BLKM*32];
  __shared__ __align__(16) bf16 Bs[128*32];
  const int tid = threadIdx.x, w = tid>>6, lane = tid&63;
  const int quad = lane>>4, l16 = lane&15;
  const int wm = w&1, wn = w>>1;
  const int tn = blockIdx.x, tm = blockIdx.y;

  // staging: wave w issue covers rows w*16 + (lane>>2), 16B chunk (lane&3)
  const int lrow = lane>>2, lk8 = (lane&3)*8;
  const bf16* Ag = A  + (size_t)(tm*BLKM + w*16 + lrow)*K + lk8;
  const bf16* Bg = Bt + (size_t)(tn*128  + w*16 + lrow)*K + lk8;
  bf16* AsW = As + w*512;   // wave-uniform LDS base (1KB per wave-issue)
  bf16* BsW = Bs + w*512;

  const bf16* Ar = As + (wm*HM + l16)*32 + quad*8;
  const bf16* Br = Bs + (wn*64 + l16)*32 + quad*8;

  f32x4 acc[RM][4] = {};

  for(int k0 = 0; k0 < K; k0 += 32){
    GLL16(Ag, AsW);
    if(BLKM == 128) GLL16(Ag + (size_t)64*K, AsW + 2048);
    GLL16(Bg, BsW);
    GLL16(Bg + (size_t)64*K, BsW + 2048);
    Ag += 32; Bg += 32;
    __syncthreads();                       // drains vmcnt -> LDS tiles valid
    bf16x8 af[RM], bfr[4];
#pragma unroll
    for(int r=0;r<RM;r++) af[r]  = *(const bf16x8*)(Ar + r*16*32);
#pragma unroll
    for(int c=0;c<4;c++)  bfr[c] = *(const bf16x8*)(Br + c*16*32);
#pragma unroll
    for(int r=0;r<RM;r++)
#pragma unroll
      for(int c=0;c<4;c++)
        acc[r][c] = MFMA(af[r], bfr[c], acc[r][c]);
    __syncthreads();                       // reads done before next stage
  }

  // C/D: col = lane&15, row = quad*4 + reg
#pragma unroll
  for(int r=0;r<RM;r++){
    const int grow0 = tm*BLKM + wm*HM + r*16 + quad*4;
#pragma unroll
    for(int c=0;c<4;c++){
      const int gcol = tn*128 + wn*64 + c*16 + l16;
      float bv = 0.0f;
      if constexpr (EPI==1 || EPI==2 || EPI==3) bv = bias[gcol];
#pragma unroll
      for(int g=0; g<4; g++){
        const float vv = acc[r][c][g] + bv;
        if constexpr (EPI==4){
          const int seg = gcol >> 10, col = gcol & 1023;
          bf16* op = (seg==0) ? outb : (seg==1 ? o2 : o3);
          op[(size_t)(grow0+g)*1024 + col] = (bf16)vv;
        } else {
          const size_t idx = (size_t)(grow0+g)*N + gcol;
          if constexpr (EPI==1){
            outb[idx] = (bf16)vv;
          } else if constexpr (EPI==2){
            outf[idx] = res[idx] + vv;
          } else {
            const float gel = 0.5f*vv*(1.0f + erff(vv*0.70710678118654752f));
            outf[idx] = res[idx] + gel;
          }
        }
      }
    }
  }
}

// ---------------- fused causal attention, LDS-staged K/V ----------------
// grid (16 qtiles, 64 b*h), 256 thr = 4 waves; wave w owns q-rows qtile*64+w*16..+15
// inner loop: 64-key blocks; K staged as Ks[key][hd], V transposed to Vs[hd][key]
constexpr int LDK = 72;   // pad 64->72: 2-way bank alias only (free, m136)

__global__ __launch_bounds__(256,4) void attn_kernel(
    const bf16* __restrict__ Q, const bf16* __restrict__ Km,
    const bf16* __restrict__ V, bf16* __restrict__ O)
{
  __shared__ __align__(16) bf16 Ks[64*LDK];
  __shared__ __align__(16) bf16 Vs[64*LDK];
  __shared__ __align__(16) bf16 Ps[4][16*LDK];
  const int qtile = blockIdx.x, bh = blockIdx.y;
  const int b = bh >> 4, h = bh & 15;
  const int tid = threadIdx.x;
  const int w = tid>>6, lane = tid&63, quad = lane>>4, l16 = lane&15;
  const size_t base = (size_t)b*1024*1024 + (size_t)h*64;
  const int qrow0 = qtile*64 + w*16;
  bf16* pl = Ps[w];

  const bf16* qp = Q + base + (size_t)(qrow0 + l16)*1024 + quad*8;
  bf16x8 aq0 = *(const bf16x8*)qp;          // A frag, hd 0..31
  bf16x8 aq1 = *(const bf16x8*)(qp + 32);   // A frag, hd 32..63

  f32x4 o[4] = {};
  float mrun[4] = {-INFINITY,-INFINITY,-INFINITY,-INFINITY};
  float lrun[4] = {0.f,0.f,0.f,0.f};
  const f32x4 zf = {0.f,0.f,0.f,0.f};

  // staging map: thread -> (row r0 = tid/8 and r0+32, hd chunk (tid&7)*8)
  const int r0 = tid>>3, c0 = (tid&7)*8;
  const bf16* kg = Km + base + c0;
  const bf16* vg = V  + base + c0;

  for(int kb = 0; kb <= qtile; kb++){
    __syncthreads();   // prev block's LDS reads complete
    {
      const size_t g0 = (size_t)(kb*64 + r0)*1024;
      const size_t g1 = g0 + (size_t)32*1024;
      bf16x8 k0v = *(const bf16x8*)(kg + g0);
      bf16x8 k1v = *(const bf16x8*)(kg + g1);
      bf16x8 v0v = *(const bf16x8*)(vg + g0);
      bf16x8 v1v = *(const bf16x8*)(vg + g1);
      *(bf16x8*)(Ks + r0*LDK + c0)      = k0v;
      *(bf16x8*)(Ks + (r0+32)*LDK + c0) = k1v;
#pragma unroll
      for(int j=0;j<8;j++){
        Vs[(c0+j)*LDK + r0]      = v0v[j];
        Vs[(c0+j)*LDK + r0 + 32] = v1v[j];
      }
    }
    __syncthreads();   // tiles visible

    // QK^T: 4 key-subtiles x 2 hd-chunks
    f32x4 s[4];
#pragma unroll
    for(int c=0;c<4;c++){
      bf16x8 k0f = *(const bf16x8*)(Ks + (c*16+l16)*LDK + quad*8);
      bf16x8 k1f = *(const bf16x8*)(Ks + (c*16+l16)*LDK + 32 + quad*8);
      s[c] = MFMA(aq0, k0f, zf);
      s[c] = MFMA(aq1, k1f, s[c]);
    }

    const bool lastb = (kb == qtile);   // only the diagonal block needs masking
#pragma unroll
    for(int r=0;r<4;r++){
      const int row = qrow0 + quad*4 + r;
      float v0 = s[0][r]*0.03125f, v1 = s[1][r]*0.03125f;
      float v2 = s[2][r]*0.03125f, v3 = s[3][r]*0.03125f;
      if(lastb){
        const int cb = kb*64 + l16;
        if(cb      > row) v0 = -INFINITY;
        if(cb + 16 > row) v1 = -INFINITY;
        if(cb + 32 > row) v2 = -INFINITY;
        if(cb + 48 > row) v3 = -INFINITY;
      }
      float mx = fmaxf(fmaxf(v0,v1), fmaxf(v2,v3));
#pragma unroll
      for(int off=1; off<16; off<<=1) mx = fmaxf(mx, __shfl_xor(mx, off));
      const float mnew  = fmaxf(mrun[r], mx);
      const float alpha = __expf(mrun[r] - mnew);
      const float p0 = __expf(v0 - mnew), p1 = __expf(v1 - mnew);
      const float p2 = __expf(v2 - mnew), p3 = __expf(v3 - mnew);
      float rs = (p0+p1)+(p2+p3);
#pragma unroll
      for(int off=1; off<16; off<<=1) rs += __shfl_xor(rs, off);
      lrun[r] = lrun[r]*alpha + rs;
      mrun[r] = mnew;
#pragma unroll
      for(int c=0;c<4;c++) o[c][r] *= alpha;
      const int pr = (quad*4+r)*LDK;
      pl[pr + l16]      = (bf16)p0;
      pl[pr + 16 + l16] = (bf16)p1;
      pl[pr + 32 + l16] = (bf16)p2;
      pl[pr + 48 + l16] = (bf16)p3;
    }

    // P (A-layout via per-wave LDS) @ V (B-frags from transposed Vs)
    bf16x8 ap0 = *(const bf16x8*)(pl + l16*LDK + quad*8);
    bf16x8 ap1 = *(const bf16x8*)(pl + l16*LDK + 32 + quad*8);
#pragma unroll
    for(int c=0;c<4;c++){
      bf16x8 bv0 = *(const bf16x8*)(Vs + (c*16+l16)*LDK + quad*8);
      bf16x8 bv1 = *(const bf16x8*)(Vs + (c*16+l16)*LDK + 32 + quad*8);
      o[c] = MFMA(ap0, bv0, o[c]);
      o[c] = MFMA(ap1, bv1, o[c]);
    }
  }

#pragma unroll
  for(int c=0;c<4;c++){
#pragma unroll
    for(int g=0;g<4;g++){
      const int row = qrow0 + quad*4 + g;
      O[base + (size_t)row*1024 + c*16 + l16] = (bf16)(o[c][g] / lrun[g]);
    }
  }
}

// ---------------- launch ----------------
extern "C" void kernel_launch(void* const* d_in, const int* in_sizes, int n_in,
                              void* d_out, int out_size, void* d_ws, size_t ws_size,
                              hipStream_t stream)
{
  const float* x_in = (const float*)d_in[0];
  const float* emb  = (const float*)d_in[1];
  const float* Wq   = (const float*)d_in[2];
  const float* Wk   = (const float*)d_in[3];
  const float* Wv   = (const float*)d_in[4];
  const float* fcw  = (const float*)d_in[5];
  const float* fcb  = (const float*)d_in[6];
  const float* ln1w = (const float*)d_in[7];
  const float* ln1b = (const float*)d_in[8];
  const float* ln2w = (const float*)d_in[9];
  const float* ln2b = (const float*)d_in[10];
  const float* w1   = (const float*)d_in[11];
  const float* b1   = (const float*)d_in[12];
  const float* w2   = (const float*)d_in[13];
  const float* b2   = (const float*)d_in[14];
  const float* w3   = (const float*)d_in[15];
  const float* b3   = (const float*)d_in[16];

  char* ws = (char*)d_ws;
  const size_t MB = 1024*1024;
  float* cur   = (float*)(ws + 0);
  float* x1    = (float*)(ws + 16*MB);
  float* newe  = (float*)(ws + 32*MB);
  bf16*  hb    = (bf16*)(ws + 48*MB);
  bf16*  attnb = (bf16*)(ws + 56*MB);
  bf16*  qb    = (bf16*)(ws + 64*MB);
  bf16*  kbuf  = (bf16*)(ws + 72*MB);
  bf16*  vbuf  = (bf16*)(ws + 80*MB);
  bf16*  m1b   = (bf16*)(ws + 88*MB);
  bf16*  wqkvT = (bf16*)(ws + 104*MB);   // [3072][1024] contiguous: q rows 0..1023, k, v
  bf16*  fcT   = (bf16*)(ws + 110*MB);
  bf16*  w1T   = (bf16*)(ws + 112*MB);
  bf16*  w2T   = (bf16*)(ws + 116*MB);
  bf16*  w3T   = (bf16*)(ws + 120*MB);

  bf16* wqT = wqkvT;
  bf16* wkT = wqkvT + 1024*1024;
  bf16* wvT = wqkvT + 2*1024*1024;

  pack_qkv_kernel<<<4096,256,0,stream>>>(Wq, wqT);
  pack_qkv_kernel<<<4096,256,0,stream>>>(Wk, wkT);
  pack_qkv_kernel<<<4096,256,0,stream>>>(Wv, wvT);
  pack_t_kernel<<<4096,256,0,stream>>>(fcw, fcT, 1024, 1024);
  pack_t_kernel<<<8192,256,0,stream>>>(w1,  w1T, 1024, 2048);
  pack_t_kernel<<<8192,256,0,stream>>>(w2,  w2T, 2048, 1024);
  pack_t_kernel<<<4096,256,0,stream>>>(w3,  w3T, 1024, 1024);

  for(int t=0; t<8; t++){
    const float* xs = (t==0) ? x_in : cur;
    const float* as = (t==0) ? x_in : newe;
    add_ln_kernel<<<4096,256,0,stream>>>(xs, as, emb + t*1024, ln1w, ln1b, cur, hb);
    // fused q,k,v = h @ [Wq;Wk;Wv]   (N=3072, 768 blocks, 3/CU)
    gemm_kernel<4,128><<<dim3(24,32),256,0,stream>>>(hb, wqkvT, nullptr, qb, kbuf, vbuf, nullptr, nullptr, 3072, 1024);
    attn_kernel<<<dim3(16,64),256,0,stream>>>(qb, kbuf, vbuf, attnb);
    // x1 = cur + attn @ fc_w + fc_b   (N=1024: BLKM=64 -> 512 blocks, 2/CU)
    gemm_kernel<2,64><<<dim3(8,64),256,0,stream>>>(attnb, fcT, x1, nullptr, nullptr, nullptr, fcb, cur, 1024, 1024);
    add_ln_kernel<<<4096,256,0,stream>>>(x1, nullptr, nullptr, ln2w, ln2b, nullptr, hb);
    gemm_kernel<1,128><<<dim3(16,32),256,0,stream>>>(hb,  w1T, nullptr, m1b,   nullptr, nullptr, b1, nullptr, 2048, 1024);
    gemm_kernel<1,64><<<dim3(8,64),256,0,stream>>>(m1b,   w2T, nullptr, attnb, nullptr, nullptr, b2, nullptr, 1024, 2048);
    float* mout = (t==7) ? (float*)d_out : newe;
    gemm_kernel<3,64><<<dim3(8,64),256,0,stream>>>(attnb, w3T, mout, nullptr, nullptr, nullptr, b3, x1, 1024, 1024);
  }
}

// Round 3
// 1570.952 us; speedup vs baseline: 1.7629x; 1.3676x over previous
//
#include <hip/hip_runtime.h>
#include <hip/hip_bf16.h>
#include <math.h>

typedef __bf16 bf16;
typedef __bf16 bf16x8 __attribute__((ext_vector_type(8)));
typedef __bf16 bf16x4 __attribute__((ext_vector_type(4)));
typedef short  s16x4  __attribute__((ext_vector_type(4)));
typedef float  f32x4  __attribute__((ext_vector_type(4)));

#define MFMA32(a,b,c) __builtin_amdgcn_mfma_f32_16x16x32_bf16((a),(b),(c),0,0,0)
#define MFMA16(a,b,c) __builtin_amdgcn_mfma_f32_16x16x16bf16_1k((a),(b),(c),0,0,0)
// async global->LDS, 16B per lane; LDS dest is wave-uniform base + lane*16 (m104/m108)
#define GLL16(gp, lp) __builtin_amdgcn_global_load_lds(\
    (const __attribute__((address_space(1))) void*)(gp), \
    (__attribute__((address_space(3))) void*)(lp), 16, 0, 0)

__device__ __forceinline__ float wave_sum(float v){
#pragma unroll
  for(int off=1; off<64; off<<=1) v += __shfl_xor(v, off);
  return v;
}

// ---------------- fused (add) + layernorm -> bf16 ----------------
__global__ __launch_bounds__(256) void add_ln_kernel(
    const float* __restrict__ xsrc, const float* __restrict__ addsrc,
    const float* __restrict__ emb,
    const float* __restrict__ gw, const float* __restrict__ gb,
    float* __restrict__ xout, bf16* __restrict__ hout)
{
  const int row = blockIdx.x;
  const int t = threadIdx.x;
  const size_t rbase = (size_t)row * 1024;
  float4 x = ((const float4*)(xsrc + rbase))[t];
  if(addsrc){
    float4 a = ((const float4*)(addsrc + rbase))[t];
    x.x += a.x; x.y += a.y; x.z += a.z; x.w += a.w;
  }
  if(emb){
    float4 e = ((const float4*)emb)[t];
    x.x += e.x; x.y += e.y; x.z += e.z; x.w += e.w;
  }
  if(xout) ((float4*)(xout + rbase))[t] = x;

  float s = x.x + x.y + x.z + x.w;
  float q = x.x*x.x + x.y*x.y + x.z*x.z + x.w*x.w;
  s = wave_sum(s); q = wave_sum(q);
  __shared__ float red[8];
  const int w = t >> 6;
  if((t & 63) == 0){ red[w] = s; red[4+w] = q; }
  __syncthreads();
  s = red[0]+red[1]+red[2]+red[3];
  q = red[4]+red[5]+red[6]+red[7];
  const float mean = s * (1.0f/1024.0f);
  const float var  = q * (1.0f/1024.0f) - mean*mean;
  const float inv  = rsqrtf(var + 1e-5f);

  float4 wv = ((const float4*)gw)[t];
  float4 bv = ((const float4*)gb)[t];
  bf16x4 hv;
  hv[0] = (bf16)((x.x - mean)*inv*wv.x + bv.x);
  hv[1] = (bf16)((x.y - mean)*inv*wv.y + bv.y);
  hv[2] = (bf16)((x.z - mean)*inv*wv.z + bv.z);
  hv[3] = (bf16)((x.w - mean)*inv*wv.w + bv.w);
  *(bf16x4*)(hout + rbase + t*4) = hv;
}

// ---------------- weight packing ----------------
__global__ __launch_bounds__(256) void pack_qkv_kernel(const float* __restrict__ W, bf16* __restrict__ Wt){
  const int i = blockIdx.x*256 + threadIdx.x;
  const int n = i >> 10, d = i & 1023;
  const int h = n >> 6, kk = n & 63;
  Wt[i] = (bf16)W[h*65536 + d*64 + kk];
}
__global__ __launch_bounds__(256) void pack_t_kernel(const float* __restrict__ W, bf16* __restrict__ Wt, int Kd, int Nd){
  const int i = blockIdx.x*256 + threadIdx.x;
  const int n = i / Kd, k = i - n*Kd;
  Wt[i] = (bf16)W[(size_t)k*Nd + n];
}
__global__ __launch_bounds__(256) void pack_cast_kernel(const float* __restrict__ W, bf16* __restrict__ Wb){
  const int i = blockIdx.x*256 + threadIdx.x;
  Wb[i] = (bf16)W[i];
}
// out[n] = sum_k bin[k]*WT[n][k] + badd[n]   (WT bf16 n-major)
__global__ __launch_bounds__(256) void biasmv_kernel(const float* __restrict__ bin, const bf16* __restrict__ WT,
                                                     const float* __restrict__ badd, float* __restrict__ out, int Kd){
  const int n = blockIdx.x, t = threadIdx.x;
  float acc = 0.f;
  for(int k=t; k<Kd; k+=256) acc += bin[k]*(float)WT[(size_t)n*Kd + k];
  acc = wave_sum(acc);
  __shared__ float red[4];
  if((t&63)==0) red[t>>6] = acc;
  __syncthreads();
  if(t==0) out[n] = red[0]+red[1]+red[2]+red[3] + badd[n];
}

// ---------------- bf16 MFMA GEMM (m97 structure):  C[M,N] = A[M,K] * Bt[N,K]^T ----------------
// block: BLKM x 128, BK=32, 256 thr = 4 waves (2x2), wave tile (BLKM/2) x 64
// EPI: 0 plain->bf16 ; 1 +bias->bf16 ; 2 res+acc+bias->f32 ; 3 res+gelu(acc+bias)->f32 ;
//      4 qkv split: q,k plain bf16 token-major, v written TRANSPOSED per-head -> o3[bh*64+kk][t]
template<int EPI, int BLKM>
__global__ __launch_bounds__(256,2) void gemm_kernel(
    const bf16* __restrict__ A, const bf16* __restrict__ Bt,
    float* __restrict__ outf, bf16* __restrict__ outb,
    bf16* __restrict__ o2, bf16* __restrict__ o3,
    const float* __restrict__ bias, const float* __restrict__ res,
    int N, int K)
{
  constexpr int RM = BLKM/32;
  constexpr int HM = BLKM/2;
  __shared__ __align__(16) bf16 As[BLKM*32];
  __shared__ __align__(16) bf16 Bs[128*32];
  const int tid = threadIdx.x, w = tid>>6, lane = tid&63;
  const int quad = lane>>4, l16 = lane&15;
  const int wm = w&1, wn = w>>1;
  const int tn = blockIdx.x, tm = blockIdx.y;

  const int lrow = lane>>2, lk8 = (lane&3)*8;
  const bf16* Ag = A  + (size_t)(tm*BLKM + w*16 + lrow)*K + lk8;
  const bf16* Bg = Bt + (size_t)(tn*128  + w*16 + lrow)*K + lk8;
  bf16* AsW = As + w*512;
  bf16* BsW = Bs + w*512;

  const bf16* Ar = As + (wm*HM + l16)*32 + quad*8;
  const bf16* Br = Bs + (wn*64 + l16)*32 + quad*8;

  f32x4 acc[RM][4] = {};

  for(int k0 = 0; k0 < K; k0 += 32){
    GLL16(Ag, AsW);
    if(BLKM == 128) GLL16(Ag + (size_t)64*K, AsW + 2048);
    GLL16(Bg, BsW);
    GLL16(Bg + (size_t)64*K, BsW + 2048);
    Ag += 32; Bg += 32;
    __syncthreads();
    bf16x8 af[RM], bfr[4];
#pragma unroll
    for(int r=0;r<RM;r++) af[r]  = *(const bf16x8*)(Ar + r*16*32);
#pragma unroll
    for(int c=0;c<4;c++)  bfr[c] = *(const bf16x8*)(Br + c*16*32);
#pragma unroll
    for(int r=0;r<RM;r++)
#pragma unroll
      for(int c=0;c<4;c++)
        acc[r][c] = MFMA32(af[r], bfr[c], acc[r][c]);
    __syncthreads();
  }

  // C/D: col = lane&15, row = quad*4 + reg
#pragma unroll
  for(int r=0;r<RM;r++){
    const int grow0 = tm*BLKM + wm*HM + r*16 + quad*4;
#pragma unroll
    for(int c=0;c<4;c++){
      const int gcol = tn*128 + wn*64 + c*16 + l16;
      float bv = 0.0f;
      if constexpr (EPI==1 || EPI==2 || EPI==3) bv = bias[gcol];
      if constexpr (EPI==4){
        const int seg = gcol >> 10;          // wave-uniform (tiles never straddle 1024)
        if(seg < 2){
          bf16* op = (seg==0) ? outb : o2;
          const int col = gcol & 1023;
#pragma unroll
          for(int g=0; g<4; g++)
            op[(size_t)(grow0+g)*1024 + col] = (bf16)acc[r][c][g];
        } else {
          const int col0 = gcol & 1023, hh = col0>>6, kk = col0&63;
          const int btok = grow0>>10, t0 = grow0&1023;
          bf16x4 pv;
#pragma unroll
          for(int g=0; g<4; g++) pv[g] = (bf16)acc[r][c][g];
          *(bf16x4*)(o3 + ((size_t)(btok*16+hh)*64 + kk)*1024 + t0) = pv;
        }
      } else {
#pragma unroll
        for(int g=0; g<4; g++){
          const float vv = acc[r][c][g] + bv;
          const size_t idx = (size_t)(grow0+g)*N + gcol;
          if constexpr (EPI<=1){
            outb[idx] = (bf16)vv;
          } else if constexpr (EPI==2){
            outf[idx] = res[idx] + vv;
          } else {
            const float gel = 0.5f*vv*(1.0f + erff(vv*0.70710678118654752f));
            outf[idx] = res[idx] + gel;
          }
        }
      }
    }
  }
}

// ---------------- fused causal attention, S^T formulation ----------------
// S^T = K·Q^T (16x16x32); softmax row = lane&15 (one row-state/lane);
// P^T in C-layout IS the B-operand of 16x16x16 -> O^T = V^T·P^T straight from registers.
// V^T comes pre-transposed from the QKV GEMM epilogue: Vt[(b*16+h)*64+hd][t].
constexpr int LDK = 72;   // padded rows: 144B stride -> 4-bank row shift, 2-way alias only

__global__ __launch_bounds__(256) void attn_kernel(
    const bf16* __restrict__ Q, const bf16* __restrict__ Km,
    const bf16* __restrict__ Vt, bf16* __restrict__ O)
{
  __shared__ __align__(16) bf16 Ks[64*LDK];   // Ks[key][hd]
  __shared__ __align__(16) bf16 Vs[64*LDK];   // Vs[hd][key]
  const int qtile = 15 - blockIdx.x;          // heavy blocks first
  const int bh = blockIdx.y;
  const int b = bh >> 4, h = bh & 15;
  const int tid = threadIdx.x;
  const int w = tid>>6, lane = tid&63, quad = lane>>4, l16 = lane&15;
  const size_t qbase = (size_t)b*1024*1024 + (size_t)h*64;
  const size_t vbase = (size_t)(bh*64)*1024;
  const int qrow0 = qtile*64 + w*16;
  const int myrow = qrow0 + l16;

  // Q as B-frag: n=l16 (qrow), k=quad*8+j (hd)
  const bf16* qp = Q + qbase + (size_t)myrow*1024 + quad*8;
  bf16x8 bq0 = *(const bf16x8*)qp;
  bf16x8 bq1 = *(const bf16x8*)(qp + 32);

  f32x4 o[4] = {};                 // O^T: hd = d*16+quad*4+g, qrow = l16
  float mrun = -INFINITY, lrun = 0.f;
  const f32x4 zf = {0.f,0.f,0.f,0.f};

  const int r0 = tid>>3, c0 = (tid&7)*8;

  for(int kb = 0; kb <= qtile; kb++){
    __syncthreads();
    {
      const bf16* kg = Km + qbase + (size_t)(kb*64 + r0)*1024 + c0;
      bf16x8 a0 = *(const bf16x8*)kg;
      bf16x8 a1 = *(const bf16x8*)(kg + (size_t)32*1024);
      const bf16* vg = Vt + vbase + (size_t)r0*1024 + kb*64 + c0;
      bf16x8 v0 = *(const bf16x8*)vg;
      bf16x8 v1 = *(const bf16x8*)(vg + (size_t)32*1024);
      *(bf16x8*)(Ks + r0*LDK + c0)      = a0;
      *(bf16x8*)(Ks + (r0+32)*LDK + c0) = a1;
      *(bf16x8*)(Vs + r0*LDK + c0)      = v0;   // rows are hd (already transposed)
      *(bf16x8*)(Vs + (r0+32)*LDK + c0) = v1;
    }
    __syncthreads();

    const int rel = qrow0 + 15 - kb*64;              // >= 15 always
    const int nc  = (rel >= 48) ? 4 : ((rel>>4) + 1); // active 16-key subtiles (wave-uniform)
    const bool diag = (kb == qtile);

    // S^T: A = K (m=key), B = Q (n=qrow)
    f32x4 s[4];
#pragma unroll
    for(int c=0;c<4;c++){
      if(c >= nc) continue;
      bf16x8 ak0 = *(const bf16x8*)(Ks + (c*16+l16)*LDK + quad*8);
      bf16x8 ak1 = *(const bf16x8*)(Ks + (c*16+l16)*LDK + 32 + quad*8);
      s[c] = MFMA32(ak0, bq0, zf);
      s[c] = MFMA32(ak1, bq1, s[c]);
    }

    float mx = -INFINITY;
#pragma unroll
    for(int c=0;c<4;c++){
      if(c >= nc) continue;
#pragma unroll
      for(int g=0;g<4;g++){
        float v = s[c][g]*0.03125f;                  // 1024^-0.5
        if(diag){
          const int key = kb*64 + c*16 + quad*4 + g;
          if(key > myrow) v = -INFINITY;
        }
        s[c][g] = v;
        mx = fmaxf(mx, v);
      }
    }
    mx = fmaxf(mx, __shfl_xor(mx, 16));
    mx = fmaxf(mx, __shfl_xor(mx, 32));

    const float mnew  = fmaxf(mrun, mx);
    const float alpha = __expf(mrun - mnew);
    float rs = 0.f;
    s16x4 p[4];
#pragma unroll
    for(int c=0;c<4;c++){
      if(c >= nc) continue;
      bf16x4 pb;
#pragma unroll
      for(int g=0;g<4;g++){
        const float e = __expf(s[c][g] - mnew);
        rs += e;
        pb[g] = (bf16)e;
      }
      p[c] = __builtin_bit_cast(s16x4, pb);
    }
    rs += __shfl_xor(rs, 16);
    rs += __shfl_xor(rs, 32);
    lrun = lrun*alpha + rs;
    mrun = mnew;
#pragma unroll
    for(int d=0;d<4;d++) o[d] *= alpha;

    // O^T += V^T · P^T  (16x16x16, P^T direct from registers)
#pragma unroll
    for(int c=0;c<4;c++){
      if(c >= nc) continue;
#pragma unroll
      for(int d=0;d<4;d++){
        bf16x4 av = *(const bf16x4*)(Vs + (d*16+l16)*LDK + c*16 + quad*4);
        o[d] = MFMA16(__builtin_bit_cast(s16x4, av), p[c], o[d]);
      }
    }
  }

  // O^T -> LDS bounce (reuse Ks) -> coalesced global store
  __syncthreads();
  bf16* ot = Ks + w*(16*LDK);
  const float inv = 1.0f / lrun;
#pragma unroll
  for(int d=0;d<4;d++)
#pragma unroll
    for(int g=0;g<4;g++)
      ot[l16*LDK + d*16 + quad*4 + g] = (bf16)(o[d][g]*inv);
  // per-wave region: in-order DS, compiler inserts lgkmcnt before reads
#pragma unroll
  for(int p2=0;p2<2;p2++){
    const int qr = (lane>>3) + 8*p2, hd0 = (lane&7)*8;
    bf16x8 val = *(const bf16x8*)(ot + qr*LDK + hd0);
    *(bf16x8*)(O + qbase + (size_t)(qrow0+qr)*1024 + hd0) = val;
  }
}

// ---------------- launch ----------------
extern "C" void kernel_launch(void* const* d_in, const int* in_sizes, int n_in,
                              void* d_out, int out_size, void* d_ws, size_t ws_size,
                              hipStream_t stream)
{
  const float* x_in = (const float*)d_in[0];
  const float* emb  = (const float*)d_in[1];
  const float* Wq   = (const float*)d_in[2];
  const float* Wk   = (const float*)d_in[3];
  const float* Wv   = (const float*)d_in[4];
  const float* fcw  = (const float*)d_in[5];
  const float* fcb  = (const float*)d_in[6];
  const float* ln1w = (const float*)d_in[7];
  const float* ln1b = (const float*)d_in[8];
  const float* ln2w = (const float*)d_in[9];
  const float* ln2b = (const float*)d_in[10];
  const float* w1   = (const float*)d_in[11];
  const float* b1   = (const float*)d_in[12];
  const float* w2   = (const float*)d_in[13];
  const float* b2   = (const float*)d_in[14];
  const float* w3   = (const float*)d_in[15];
  const float* b3   = (const float*)d_in[16];

  char* ws = (char*)d_ws;
  const size_t MB = 1024*1024;
  float* cur    = (float*)(ws + 0);
  float* x1     = (float*)(ws + 16*MB);
  float* newe   = (float*)(ws + 32*MB);
  bf16*  hb     = (bf16*)(ws + 48*MB);
  bf16*  attnb  = (bf16*)(ws + 56*MB);
  bf16*  qb     = (bf16*)(ws + 64*MB);
  bf16*  kbuf   = (bf16*)(ws + 72*MB);
  bf16*  vtb    = (bf16*)(ws + 80*MB);    // V^T per-head: [(b*16+h)*64+hd][t]
  bf16*  w1pl   = (bf16*)(ws + 88*MB);    // w1 plain cast [1024][2048]
  bf16*  T12    = (bf16*)(ws + 92*MB);    // w1@w2 [1024][1024]
  bf16*  wqkvT  = (bf16*)(ws + 96*MB);    // [3072][1024]
  bf16*  fcT    = (bf16*)(ws + 102*MB);
  bf16*  w2T    = (bf16*)(ws + 104*MB);   // [1024][2048]
  bf16*  w3T    = (bf16*)(ws + 108*MB);   // [1024][1024]
  bf16*  WeffT  = (bf16*)(ws + 110*MB);   // (w1w2w3)^T [1024][1024]
  float* tmpb   = (float*)(ws + 112*MB);
  float* beff   = (float*)(ws + 112*MB + 8192);

  bf16* wqT = wqkvT;
  bf16* wkT = wqkvT + 1024*1024;
  bf16* wvT = wqkvT + 2*1024*1024;

  // one-time packing + MLP weight composition
  pack_qkv_kernel<<<4096,256,0,stream>>>(Wq, wqT);
  pack_qkv_kernel<<<4096,256,0,stream>>>(Wk, wkT);
  pack_qkv_kernel<<<4096,256,0,stream>>>(Wv, wvT);
  pack_t_kernel<<<4096,256,0,stream>>>(fcw, fcT, 1024, 1024);
  pack_t_kernel<<<8192,256,0,stream>>>(w2,  w2T, 2048, 1024);
  pack_t_kernel<<<4096,256,0,stream>>>(w3,  w3T, 1024, 1024);
  pack_cast_kernel<<<8192,256,0,stream>>>(w1, w1pl);
  // T12 = w1@w2 ; WeffT = w3T @ T12^T = (w1@w2@w3)^T
  gemm_kernel<0,64><<<dim3(8,16),256,0,stream>>>(w1pl, w2T, nullptr, T12,   nullptr, nullptr, nullptr, nullptr, 1024, 2048);
  gemm_kernel<0,64><<<dim3(8,16),256,0,stream>>>(w3T,  T12, nullptr, WeffT, nullptr, nullptr, nullptr, nullptr, 1024, 1024);
  // beff = ((b1@w2)+b2)@w3 + b3
  biasmv_kernel<<<1024,256,0,stream>>>(b1,   w2T, b2, tmpb, 2048);
  biasmv_kernel<<<1024,256,0,stream>>>(tmpb, w3T, b3, beff, 1024);

  for(int t=0; t<8; t++){
    const float* xs = (t==0) ? x_in : cur;
    const float* as = (t==0) ? x_in : newe;
    add_ln_kernel<<<4096,256,0,stream>>>(xs, as, emb + t*1024, ln1w, ln1b, cur, hb);
    // q,k (token-major) and v (transposed per-head) = h @ [Wq;Wk;Wv]
    gemm_kernel<4,128><<<dim3(24,32),256,0,stream>>>(hb, wqkvT, nullptr, qb, kbuf, vtb, nullptr, nullptr, 3072, 1024);
    attn_kernel<<<dim3(16,64),256,0,stream>>>(qb, kbuf, vtb, attnb);
    // x1 = cur + attn @ fc_w + fc_b
    gemm_kernel<2,64><<<dim3(8,64),256,0,stream>>>(attnb, fcT, x1, nullptr, nullptr, nullptr, fcb, cur, 1024, 1024);
    add_ln_kernel<<<4096,256,0,stream>>>(x1, nullptr, nullptr, ln2w, ln2b, nullptr, hb);
    // newe = x1 + gelu(h2 @ Weff + beff)
    float* mout = (t==7) ? (float*)d_out : newe;
    gemm_kernel<3,64><<<dim3(8,64),256,0,stream>>>(hb, WeffT, mout, nullptr, nullptr, nullptr, beff, x1, 1024, 1024);
  }
}

// Round 4
// 1441.425 us; speedup vs baseline: 1.9213x; 1.0899x over previous
//
#include <hip/hip_runtime.h>
#include <hip/hip_bf16.h>
#include <math.h>

typedef __bf16 bf16;
typedef __bf16 bf16x8 __attribute__((ext_vector_type(8)));
typedef __bf16 bf16x4 __attribute__((ext_vector_type(4)));
typedef short  s16x4  __attribute__((ext_vector_type(4)));
typedef float  f32x4  __attribute__((ext_vector_type(4)));

#define MFMA32(a,b,c) __builtin_amdgcn_mfma_f32_16x16x32_bf16((a),(b),(c),0,0,0)
#define MFMA16(a,b,c) __builtin_amdgcn_mfma_f32_16x16x16bf16_1k((a),(b),(c),0,0,0)
// async global->LDS, 16B per lane; LDS dest is wave-uniform base + lane*16 (m104/m108)
#define GLL16(gp, lp) __builtin_amdgcn_global_load_lds(\
    (const __attribute__((address_space(1))) void*)(gp), \
    (__attribute__((address_space(3))) void*)(lp), 16, 0, 0)

__device__ __forceinline__ float wave_sum(float v){
#pragma unroll
  for(int off=1; off<64; off<<=1) v += __shfl_xor(v, off);
  return v;
}

// ---------------- fused (add) + layernorm -> bf16 ----------------
__global__ __launch_bounds__(256) void add_ln_kernel(
    const float* __restrict__ xsrc, const float* __restrict__ addsrc,
    const float* __restrict__ emb,
    const float* __restrict__ gw, const float* __restrict__ gb,
    float* __restrict__ xout, bf16* __restrict__ hout)
{
  const int row = blockIdx.x;
  const int t = threadIdx.x;
  const size_t rbase = (size_t)row * 1024;
  float4 x = ((const float4*)(xsrc + rbase))[t];
  if(addsrc){
    float4 a = ((const float4*)(addsrc + rbase))[t];
    x.x += a.x; x.y += a.y; x.z += a.z; x.w += a.w;
  }
  if(emb){
    float4 e = ((const float4*)emb)[t];
    x.x += e.x; x.y += e.y; x.z += e.z; x.w += e.w;
  }
  if(xout) ((float4*)(xout + rbase))[t] = x;

  float s = x.x + x.y + x.z + x.w;
  float q = x.x*x.x + x.y*x.y + x.z*x.z + x.w*x.w;
  s = wave_sum(s); q = wave_sum(q);
  __shared__ float red[8];
  const int w = t >> 6;
  if((t & 63) == 0){ red[w] = s; red[4+w] = q; }
  __syncthreads();
  s = red[0]+red[1]+red[2]+red[3];
  q = red[4]+red[5]+red[6]+red[7];
  const float mean = s * (1.0f/1024.0f);
  const float var  = q * (1.0f/1024.0f) - mean*mean;
  const float inv  = rsqrtf(var + 1e-5f);

  float4 wv = ((const float4*)gw)[t];
  float4 bv = ((const float4*)gb)[t];
  bf16x4 hv;
  hv[0] = (bf16)((x.x - mean)*inv*wv.x + bv.x);
  hv[1] = (bf16)((x.y - mean)*inv*wv.y + bv.y);
  hv[2] = (bf16)((x.z - mean)*inv*wv.z + bv.z);
  hv[3] = (bf16)((x.w - mean)*inv*wv.w + bv.w);
  *(bf16x4*)(hout + rbase + t*4) = hv;
}

// ---------------- weight packing ----------------
__global__ __launch_bounds__(256) void pack_qkv_kernel(const float* __restrict__ W, bf16* __restrict__ Wt){
  const int i = blockIdx.x*256 + threadIdx.x;
  const int n = i >> 10, d = i & 1023;
  const int h = n >> 6, kk = n & 63;
  Wt[i] = (bf16)W[h*65536 + d*64 + kk];
}
__global__ __launch_bounds__(256) void pack_t_kernel(const float* __restrict__ W, bf16* __restrict__ Wt, int Kd, int Nd){
  const int i = blockIdx.x*256 + threadIdx.x;
  const int n = i / Kd, k = i - n*Kd;
  Wt[i] = (bf16)W[(size_t)k*Nd + n];
}
__global__ __launch_bounds__(256) void pack_cast_kernel(const float* __restrict__ W, bf16* __restrict__ Wb){
  const int i = blockIdx.x*256 + threadIdx.x;
  Wb[i] = (bf16)W[i];
}
// out[n] = sum_k bin[k]*WT[n][k] + badd[n]   (WT bf16 n-major)
__global__ __launch_bounds__(256) void biasmv_kernel(const float* __restrict__ bin, const bf16* __restrict__ WT,
                                                     const float* __restrict__ badd, float* __restrict__ out, int Kd){
  const int n = blockIdx.x, t = threadIdx.x;
  float acc = 0.f;
  for(int k=t; k<Kd; k+=256) acc += bin[k]*(float)WT[(size_t)n*Kd + k];
  acc = wave_sum(acc);
  __shared__ float red[4];
  if((t&63)==0) red[t>>6] = acc;
  __syncthreads();
  if(t==0) out[n] = red[0]+red[1]+red[2]+red[3] + badd[n];
}

// ---------------- bf16 MFMA GEMM (m97 structure):  C[M,N] = A[M,K] * Bt[N,K]^T ----------------
template<int EPI, int BLKM>
__global__ __launch_bounds__(256,2) void gemm_kernel(
    const bf16* __restrict__ A, const bf16* __restrict__ Bt,
    float* __restrict__ outf, bf16* __restrict__ outb,
    bf16* __restrict__ o2, bf16* __restrict__ o3,
    const float* __restrict__ bias, const float* __restrict__ res,
    int N, int K)
{
  constexpr int RM = BLKM/32;
  constexpr int HM = BLKM/2;
  __shared__ __align__(16) bf16 As[BLKM*32];
  __shared__ __align__(16) bf16 Bs[128*32];
  const int tid = threadIdx.x, w = tid>>6, lane = tid&63;
  const int quad = lane>>4, l16 = lane&15;
  const int wm = w&1, wn = w>>1;
  const int tn = blockIdx.x, tm = blockIdx.y;

  const int lrow = lane>>2, lk8 = (lane&3)*8;
  const bf16* Ag = A  + (size_t)(tm*BLKM + w*16 + lrow)*K + lk8;
  const bf16* Bg = Bt + (size_t)(tn*128  + w*16 + lrow)*K + lk8;
  bf16* AsW = As + w*512;
  bf16* BsW = Bs + w*512;

  const bf16* Ar = As + (wm*HM + l16)*32 + quad*8;
  const bf16* Br = Bs + (wn*64 + l16)*32 + quad*8;

  f32x4 acc[RM][4] = {};

  for(int k0 = 0; k0 < K; k0 += 32){
    GLL16(Ag, AsW);
    if(BLKM == 128) GLL16(Ag + (size_t)64*K, AsW + 2048);
    GLL16(Bg, BsW);
    GLL16(Bg + (size_t)64*K, BsW + 2048);
    Ag += 32; Bg += 32;
    __syncthreads();
    bf16x8 af[RM], bfr[4];
#pragma unroll
    for(int r=0;r<RM;r++) af[r]  = *(const bf16x8*)(Ar + r*16*32);
#pragma unroll
    for(int c=0;c<4;c++)  bfr[c] = *(const bf16x8*)(Br + c*16*32);
#pragma unroll
    for(int r=0;r<RM;r++)
#pragma unroll
      for(int c=0;c<4;c++)
        acc[r][c] = MFMA32(af[r], bfr[c], acc[r][c]);
    __syncthreads();
  }

  // C/D: col = lane&15, row = quad*4 + reg
#pragma unroll
  for(int r=0;r<RM;r++){
    const int grow0 = tm*BLKM + wm*HM + r*16 + quad*4;
#pragma unroll
    for(int c=0;c<4;c++){
      const int gcol = tn*128 + wn*64 + c*16 + l16;
      float bv = 0.0f;
      if constexpr (EPI==1 || EPI==2 || EPI==3) bv = bias[gcol];
      if constexpr (EPI==4){
        const int seg = gcol >> 10;          // wave-uniform
        if(seg < 2){
          bf16* op = (seg==0) ? outb : o2;
          const int col = gcol & 1023;
#pragma unroll
          for(int g=0; g<4; g++)
            op[(size_t)(grow0+g)*1024 + col] = (bf16)acc[r][c][g];
        } else {
          const int col0 = gcol & 1023, hh = col0>>6, kk = col0&63;
          const int btok = grow0>>10, t0 = grow0&1023;
          bf16x4 pv;
#pragma unroll
          for(int g=0; g<4; g++) pv[g] = (bf16)acc[r][c][g];
          *(bf16x4*)(o3 + ((size_t)(btok*16+hh)*64 + kk)*1024 + t0) = pv;
        }
      } else {
#pragma unroll
        for(int g=0; g<4; g++){
          const float vv = acc[r][c][g] + bv;
          const size_t idx = (size_t)(grow0+g)*N + gcol;
          if constexpr (EPI<=1){
            outb[idx] = (bf16)vv;
          } else if constexpr (EPI==2){
            outf[idx] = res[idx] + vv;
          } else {
            const float gel = 0.5f*vv*(1.0f + erff(vv*0.70710678118654752f));
            outf[idx] = res[idx] + gel;
          }
        }
      }
    }
  }
}

// ---------------- fused causal attention: paired q-tiles + double-buffered K/V ----------------
// block p handles q-tiles A=p (light) and B=15-p (heavy): 17 tile-iterations for EVERY block
// (perfect static balance); A's key range is a subset of B's so K/V staging+fragments are shared.
// S^T = K*Q^T; P^T (C-layout) feeds O^T = V^T*P^T directly from registers (16x16x16).
constexpr int LDK = 72;   // padded rows: 144B stride -> 2-way bank alias only (free)

__global__ __launch_bounds__(256) void attn_kernel(
    const bf16* __restrict__ Q, const bf16* __restrict__ Km,
    const bf16* __restrict__ Vt, bf16* __restrict__ O)
{
  __shared__ __align__(16) bf16 Ks[2][64*LDK];   // [buf][key][hd]
  __shared__ __align__(16) bf16 Vs[2][64*LDK];   // [buf][hd][key]
  const int p  = blockIdx.x;          // 0..7
  const int qtA = p, qtB = 15 - p;
  const int bh = blockIdx.y;
  const int b = bh >> 4, h = bh & 15;
  const int tid = threadIdx.x;
  const int w = tid>>6, lane = tid&63, quad = lane>>4, l16 = lane&15;
  const size_t qbase = (size_t)b*1024*1024 + (size_t)h*64;
  const size_t vbase = (size_t)(bh*64)*1024;
  const int qrowA0 = qtA*64 + w*16, qrowB0 = qtB*64 + w*16;
  const int myrowA = qrowA0 + l16,  myrowB = qrowB0 + l16;

  // Q as B-frag: n=l16 (qrow), k=quad*8+j (hd)
  const bf16* qpA = Q + qbase + (size_t)myrowA*1024 + quad*8;
  const bf16* qpB = Q + qbase + (size_t)myrowB*1024 + quad*8;
  bf16x8 bqA0 = *(const bf16x8*)qpA, bqA1 = *(const bf16x8*)(qpA + 32);
  bf16x8 bqB0 = *(const bf16x8*)qpB, bqB1 = *(const bf16x8*)(qpB + 32);

  f32x4 oA[4] = {}, oB[4] = {};     // O^T: hd = d*16+quad*4+g, qrow = l16
  float mA = -INFINITY, lA = 0.f, mB = -INFINITY, lB = 0.f;
  const f32x4 zf = {0.f,0.f,0.f,0.f};

  // staging map: thread -> K row r0/r0+32 (keys), V row r0/r0+32 (hd), 16B chunk c0
  const int r0 = tid>>3, c0 = (tid&7)*8;
  const bf16* kg = Km + qbase + c0;
  const bf16* vg = Vt + vbase + (size_t)r0*1024 + c0;

  // prologue: stage kb=0 into buffer 0
  {
    const bf16* kgp = kg + (size_t)r0*1024;
    bf16x8 a0 = *(const bf16x8*)kgp;
    bf16x8 a1 = *(const bf16x8*)(kgp + (size_t)32*1024);
    bf16x8 v0 = *(const bf16x8*)vg;
    bf16x8 v1 = *(const bf16x8*)(vg + (size_t)32*1024);
    *(bf16x8*)(Ks[0] + r0*LDK + c0)      = a0;
    *(bf16x8*)(Ks[0] + (r0+32)*LDK + c0) = a1;
    *(bf16x8*)(Vs[0] + r0*LDK + c0)      = v0;
    *(bf16x8*)(Vs[0] + (r0+32)*LDK + c0) = v1;
  }

  for(int kb = 0; kb <= qtB; kb++){
    const int cur = kb & 1;
    const bool pf = (kb < qtB);
    __syncthreads();                       // staging of kb visible; kb-1 reads done

    // prefetch kb+1 into registers (consumed by ds_write AFTER compute -> latency hidden)
    bf16x8 nk0, nk1, nv0, nv1;
    if(pf){
      const bf16* kgp = kg + (size_t)((kb+1)*64 + r0)*1024;
      nk0 = *(const bf16x8*)kgp;
      nk1 = *(const bf16x8*)(kgp + (size_t)32*1024);
      const bf16* vgp = vg + (kb+1)*64;
      nv0 = *(const bf16x8*)vgp;
      nv1 = *(const bf16x8*)(vgp + (size_t)32*1024);
    }

    const bool diagA = (kb == qtA), diagB = (kb == qtB);
    const int ncA = (kb <= qtA) ? (diagA ? (w+1) : 4) : 0;
    const int ncB = diagB ? (w+1) : 4;     // when diagB, A is inactive -> loop bound is ncB

    const bf16* ksb = Ks[cur];
    const bf16* vsb = Vs[cur];

    // S^T: A = K (m=key), B = Q (n=qrow); shared K-frags feed both tiles
    f32x4 sA[4], sB[4];
#pragma unroll
    for(int c=0;c<4;c++){
      if(c >= ncB) continue;
      bf16x8 ak0 = *(const bf16x8*)(ksb + (c*16+l16)*LDK + quad*8);
      bf16x8 ak1 = *(const bf16x8*)(ksb + (c*16+l16)*LDK + 32 + quad*8);
      sB[c] = MFMA32(ak0, bqB0, zf);
      sB[c] = MFMA32(ak1, bqB1, sB[c]);
      if(c < ncA){
        sA[c] = MFMA32(ak0, bqA0, zf);
        sA[c] = MFMA32(ak1, bqA1, sA[c]);
      }
    }

    // ---- softmax tile B ----
    s16x4 pB[4], pA[4];
    {
      float mx = -INFINITY;
#pragma unroll
      for(int c=0;c<4;c++){
        if(c >= ncB) continue;
#pragma unroll
        for(int g=0;g<4;g++){
          float v = sB[c][g]*0.03125f;
          if(diagB){ const int key = kb*64 + c*16 + quad*4 + g; if(key > myrowB) v = -INFINITY; }
          sB[c][g] = v; mx = fmaxf(mx, v);
        }
      }
      mx = fmaxf(mx, __shfl_xor(mx, 16));
      mx = fmaxf(mx, __shfl_xor(mx, 32));
      const float mnew = fmaxf(mB, mx);
      const float alpha = __expf(mB - mnew);
      float rs = 0.f;
#pragma unroll
      for(int c=0;c<4;c++){
        if(c >= ncB) continue;
        bf16x4 pb;
#pragma unroll
        for(int g=0;g<4;g++){ const float e = __expf(sB[c][g] - mnew); rs += e; pb[g] = (bf16)e; }
        pB[c] = __builtin_bit_cast(s16x4, pb);
      }
      rs += __shfl_xor(rs, 16);
      rs += __shfl_xor(rs, 32);
      lB = lB*alpha + rs; mB = mnew;
#pragma unroll
      for(int d=0;d<4;d++) oB[d] *= alpha;
    }
    // ---- softmax tile A ----
    if(ncA > 0){
      float mx = -INFINITY;
#pragma unroll
      for(int c=0;c<4;c++){
        if(c >= ncA) continue;
#pragma unroll
        for(int g=0;g<4;g++){
          float v = sA[c][g]*0.03125f;
          if(diagA){ const int key = kb*64 + c*16 + quad*4 + g; if(key > myrowA) v = -INFINITY; }
          sA[c][g] = v; mx = fmaxf(mx, v);
        }
      }
      mx = fmaxf(mx, __shfl_xor(mx, 16));
      mx = fmaxf(mx, __shfl_xor(mx, 32));
      const float mnew = fmaxf(mA, mx);
      const float alpha = __expf(mA - mnew);
      float rs = 0.f;
#pragma unroll
      for(int c=0;c<4;c++){
        if(c >= ncA) continue;
        bf16x4 pb;
#pragma unroll
        for(int g=0;g<4;g++){ const float e = __expf(sA[c][g] - mnew); rs += e; pb[g] = (bf16)e; }
        pA[c] = __builtin_bit_cast(s16x4, pb);
      }
      rs += __shfl_xor(rs, 16);
      rs += __shfl_xor(rs, 32);
      lA = lA*alpha + rs; mA = mnew;
#pragma unroll
      for(int d=0;d<4;d++) oA[d] *= alpha;
    }

    // ---- PV: O^T += V^T * P^T, shared V-frags ----
#pragma unroll
    for(int c=0;c<4;c++){
      if(c >= ncB) continue;
#pragma unroll
      for(int d=0;d<4;d++){
        bf16x4 av = *(const bf16x4*)(vsb + (d*16+l16)*LDK + c*16 + quad*4);
        const s16x4 avs = __builtin_bit_cast(s16x4, av);
        oB[d] = MFMA16(avs, pB[c], oB[d]);
        if(c < ncA) oA[d] = MFMA16(avs, pA[c], oA[d]);
      }
    }

    // ---- write prefetched kb+1 into the other buffer ----
    if(pf){
      bf16* kd = Ks[cur^1]; bf16* vd = Vs[cur^1];
      *(bf16x8*)(kd + r0*LDK + c0)      = nk0;
      *(bf16x8*)(kd + (r0+32)*LDK + c0) = nk1;
      *(bf16x8*)(vd + r0*LDK + c0)      = nv0;
      *(bf16x8*)(vd + (r0+32)*LDK + c0) = nv1;
    }
  }

  // epilogue: O^T -> LDS bounce -> coalesced stores (separate buffers for A/B, per-wave regions)
  __syncthreads();
  {
    bf16* ot = Ks[0] + w*(16*LDK);
    const float inv = 1.0f / lA;
#pragma unroll
    for(int d=0;d<4;d++)
#pragma unroll
      for(int g=0;g<4;g++)
        ot[l16*LDK + d*16 + quad*4 + g] = (bf16)(oA[d][g]*inv);
#pragma unroll
    for(int p2=0;p2<2;p2++){
      const int qr = (lane>>3) + 8*p2, hd0 = (lane&7)*8;
      bf16x8 val = *(const bf16x8*)(ot + qr*LDK + hd0);
      *(bf16x8*)(O + qbase + (size_t)(qrowA0+qr)*1024 + hd0) = val;
    }
  }
  {
    bf16* ot = Ks[1] + w*(16*LDK);
    const float inv = 1.0f / lB;
#pragma unroll
    for(int d=0;d<4;d++)
#pragma unroll
      for(int g=0;g<4;g++)
        ot[l16*LDK + d*16 + quad*4 + g] = (bf16)(oB[d][g]*inv);
#pragma unroll
    for(int p2=0;p2<2;p2++){
      const int qr = (lane>>3) + 8*p2, hd0 = (lane&7)*8;
      bf16x8 val = *(const bf16x8*)(ot + qr*LDK + hd0);
      *(bf16x8*)(O + qbase + (size_t)(qrowB0+qr)*1024 + hd0) = val;
    }
  }
}

// ---------------- launch ----------------
extern "C" void kernel_launch(void* const* d_in, const int* in_sizes, int n_in,
                              void* d_out, int out_size, void* d_ws, size_t ws_size,
                              hipStream_t stream)
{
  const float* x_in = (const float*)d_in[0];
  const float* emb  = (const float*)d_in[1];
  const float* Wq   = (const float*)d_in[2];
  const float* Wk   = (const float*)d_in[3];
  const float* Wv   = (const float*)d_in[4];
  const float* fcw  = (const float*)d_in[5];
  const float* fcb  = (const float*)d_in[6];
  const float* ln1w = (const float*)d_in[7];
  const float* ln1b = (const float*)d_in[8];
  const float* ln2w = (const float*)d_in[9];
  const float* ln2b = (const float*)d_in[10];
  const float* w1   = (const float*)d_in[11];
  const float* b1   = (const float*)d_in[12];
  const float* w2   = (const float*)d_in[13];
  const float* b2   = (const float*)d_in[14];
  const float* w3   = (const float*)d_in[15];
  const float* b3   = (const float*)d_in[16];

  char* ws = (char*)d_ws;
  const size_t MB = 1024*1024;
  float* cur    = (float*)(ws + 0);
  float* x1     = (float*)(ws + 16*MB);
  float* newe   = (float*)(ws + 32*MB);
  bf16*  hb     = (bf16*)(ws + 48*MB);
  bf16*  attnb  = (bf16*)(ws + 56*MB);
  bf16*  qb     = (bf16*)(ws + 64*MB);
  bf16*  kbuf   = (bf16*)(ws + 72*MB);
  bf16*  vtb    = (bf16*)(ws + 80*MB);    // V^T per-head: [(b*16+h)*64+hd][t]
  bf16*  w1pl   = (bf16*)(ws + 88*MB);
  bf16*  T12    = (bf16*)(ws + 92*MB);
  bf16*  wqkvT  = (bf16*)(ws + 96*MB);
  bf16*  fcT    = (bf16*)(ws + 102*MB);
  bf16*  w2T    = (bf16*)(ws + 104*MB);
  bf16*  w3T    = (bf16*)(ws + 108*MB);
  bf16*  WeffT  = (bf16*)(ws + 110*MB);
  float* tmpb   = (float*)(ws + 112*MB);
  float* beff   = (float*)(ws + 112*MB + 8192);

  bf16* wqT = wqkvT;
  bf16* wkT = wqkvT + 1024*1024;
  bf16* wvT = wqkvT + 2*1024*1024;

  pack_qkv_kernel<<<4096,256,0,stream>>>(Wq, wqT);
  pack_qkv_kernel<<<4096,256,0,stream>>>(Wk, wkT);
  pack_qkv_kernel<<<4096,256,0,stream>>>(Wv, wvT);
  pack_t_kernel<<<4096,256,0,stream>>>(fcw, fcT, 1024, 1024);
  pack_t_kernel<<<8192,256,0,stream>>>(w2,  w2T, 2048, 1024);
  pack_t_kernel<<<4096,256,0,stream>>>(w3,  w3T, 1024, 1024);
  pack_cast_kernel<<<8192,256,0,stream>>>(w1, w1pl);
  gemm_kernel<0,64><<<dim3(8,16),256,0,stream>>>(w1pl, w2T, nullptr, T12,   nullptr, nullptr, nullptr, nullptr, 1024, 2048);
  gemm_kernel<0,64><<<dim3(8,16),256,0,stream>>>(w3T,  T12, nullptr, WeffT, nullptr, nullptr, nullptr, nullptr, 1024, 1024);
  biasmv_kernel<<<1024,256,0,stream>>>(b1,   w2T, b2, tmpb, 2048);
  biasmv_kernel<<<1024,256,0,stream>>>(tmpb, w3T, b3, beff, 1024);

  for(int t=0; t<8; t++){
    const float* xs = (t==0) ? x_in : cur;
    const float* as = (t==0) ? x_in : newe;
    add_ln_kernel<<<4096,256,0,stream>>>(xs, as, emb + t*1024, ln1w, ln1b, cur, hb);
    gemm_kernel<4,128><<<dim3(24,32),256,0,stream>>>(hb, wqkvT, nullptr, qb, kbuf, vtb, nullptr, nullptr, 3072, 1024);
    attn_kernel<<<dim3(8,64),256,0,stream>>>(qb, kbuf, vtb, attnb);
    gemm_kernel<2,64><<<dim3(8,64),256,0,stream>>>(attnb, fcT, x1, nullptr, nullptr, nullptr, fcb, cur, 1024, 1024);
    add_ln_kernel<<<4096,256,0,stream>>>(x1, nullptr, nullptr, ln2w, ln2b, nullptr, hb);
    float* mout = (t==7) ? (float*)d_out : newe;
    gemm_kernel<3,64><<<dim3(8,64),256,0,stream>>>(hb, WeffT, mout, nullptr, nullptr, nullptr, beff, x1, 1024, 1024);
  }
}